// Round 5
// baseline (263.313 us; speedup 1.0000x reference)
//
#include <hip/hip_runtime.h>
#include <stdint.h>

#define NBINS 32
#define NBATCH 64
#define NPB (512 * 512)            // pixels per batch
#define BPB 32                     // blocks per batch
#define TPB 256
#define ITERS 8                    // NPB/4 / (BPB*TPB) float4 steps

// ws layout (uint32 words):
//   [0, 2048)      obs counts   [b*32 + j]
//   [2048, 4096)   pred counts  [b*32 + j]
//   [4096, 4160)   n_masked per batch
//   [4160]         mask-format flag: 1 => bytes (bool/u8), 0 => int32
#define WS_PRED 2048
#define WS_NM   4096
#define WS_FLAG 4160
#define WS_WORDS 4161

__global__ void detect_mask_kernel(const uint32_t* __restrict__ mw,
                                   uint32_t* __restrict__ flag) {
  uint32_t v = mw[threadIdx.x];
  if (__any(v > 1u) && threadIdx.x == 0) *flag = 1u;
}

// Exact searchsorted(edges, x, 'right')-1 for edges = linspace(-3,3,33):
// every true edge is an exact multiple of 0.1875f (=3/16), so correct the
// analytic guess against edges rebuilt exactly in-register. Out-of-range /
// masked values land outside [0,31] and fall off the counting tree.
__device__ __forceinline__ int bin_of(float x) {
  float t = __builtin_fmaf(x, 5.333333492279053f, 16.0f);  // (x+3)*32/6
  int i = (int)t;
  float fi = (float)i;
  float elo = __builtin_fmaf(fi, 0.1875f, -3.0f);
  float ehi = elo + 0.1875f;
  i += (x >= ehi) ? 1 : 0;
  i -= (x < elo) ? 1 : 0;
  return i;
}

// Static select-tree increment into 8 byte-packed u32 counters.
__device__ __forceinline__ void count_one(int i, uint32_t h[8]) {
  const uint32_t inc = 1u << ((i & 3) << 3);
  const int hi = i >> 2;
#pragma unroll
  for (int r = 0; r < 8; ++r) h[r] += (hi == r) ? inc : 0u;
}

__global__ __launch_bounds__(TPB, 8) void hist_kernel(
    const float* __restrict__ obs, const float* __restrict__ pred,
    const void* __restrict__ mask, uint32_t* __restrict__ ws) {
  __shared__ uint32_t red[4][32];  // per-wave packed partials

  const int tid = threadIdx.x;
  const uint32_t is_u8 = ws[WS_FLAG];  // uniform
  const int b = blockIdx.x / BPB;
  const int chunk = blockIdx.x % BPB;

  // INTERLEAVED mapping: at step `it`, batch b's 32 blocks read one
  // contiguous 128 KB window: idx4 = b*65536 + it*8192 + chunk*256 + tid.
  // Grid-wide: 64 contiguous stream fronts per array instead of 2048.
  const size_t bbase = (size_t)b * (NPB / 4) + (size_t)chunk * TPB + tid;

  const float4* __restrict__ o4 = (const float4*)obs;
  const float4* __restrict__ p4 = (const float4*)pred;
  const uint32_t* __restrict__ mwp = (const uint32_t*)mask;
  const int4* __restrict__ mip = (const int4*)mask;

  uint32_t c[8] = {0, 0, 0, 0, 0, 0, 0, 0};  // obs byte-packed counters
  uint32_t d[8] = {0, 0, 0, 0, 0, 0, 0, 0};  // pred
  uint32_t nm_pack = 0;
  uint32_t nm_cnt = 0;

  float4 xo, xp;
  uint32_t mw_c = 0;
  int4 mi_c = {0, 0, 0, 0};
  {
    xo = o4[bbase];
    xp = p4[bbase];
    if (is_u8) mw_c = mwp[bbase]; else mi_c = mip[bbase];
  }

#pragma unroll
  for (int it = 0; it < ITERS; ++it) {
    float4 nxo = xo, nxp = xp;
    uint32_t nmw = mw_c;
    int4 nmi = mi_c;
    if (it + 1 < ITERS) {
      const size_t ni = bbase + (size_t)(it + 1) * (BPB * TPB);
      nxo = o4[ni];
      nxp = p4[ni];
      if (is_u8) nmw = mwp[ni]; else nmi = mip[ni];
    }

    bool m0, m1, m2, m3;
    if (is_u8) {
      nm_pack += mw_c;  // bytes are 0/1; <=8 per byte over 8 iters
      m0 = (mw_c & 0x000000ffu) != 0u;
      m1 = (mw_c & 0x0000ff00u) != 0u;
      m2 = (mw_c & 0x00ff0000u) != 0u;
      m3 = (mw_c & 0xff000000u) != 0u;
    } else {
      m0 = mi_c.x != 0; m1 = mi_c.y != 0; m2 = mi_c.z != 0; m3 = mi_c.w != 0;
      nm_cnt += (m0 ? 1u : 0u) + (m1 ? 1u : 0u) + (m2 ? 1u : 0u) + (m3 ? 1u : 0u);
    }

    // Fold mask into value: invalid -> 100.0 -> bin 549 -> ignored by tree.
    const float a0 = m0 ? xo.x : 1e2f, b0 = m0 ? xp.x : 1e2f;
    const float a1 = m1 ? xo.y : 1e2f, b1 = m1 ? xp.y : 1e2f;
    const float a2 = m2 ? xo.z : 1e2f, b2 = m2 ? xp.z : 1e2f;
    const float a3 = m3 ? xo.w : 1e2f, b3 = m3 ? xp.w : 1e2f;

    count_one(bin_of(a0), c); count_one(bin_of(b0), d);
    count_one(bin_of(a1), c); count_one(bin_of(b1), d);
    count_one(bin_of(a2), c); count_one(bin_of(b2), d);
    count_one(bin_of(a3), c); count_one(bin_of(b3), d);

    xo = nxo; xp = nxp; mw_c = nmw; mi_c = nmi;
  }

  // ---- n_masked: per-wave reduce, one global atomic per wave ----
  uint32_t nm = is_u8 ? ((nm_pack & 0xffu) + ((nm_pack >> 8) & 0xffu) +
                         ((nm_pack >> 16) & 0xffu) + (nm_pack >> 24))
                      : nm_cnt;
#pragma unroll
  for (int off = 32; off >= 1; off >>= 1) nm += __shfl_down(nm, off);
  if ((tid & 63) == 0) atomicAdd(&ws[WS_NM + b], nm);

  // ---- butterfly-reduce packed counters across the wave ----
#pragma unroll
  for (int m = 1; m <= 2; m <<= 1) {
#pragma unroll
    for (int r = 0; r < 8; ++r) {
      c[r] += __shfl_xor(c[r], m);
      d[r] += __shfl_xor(d[r], m);
    }
  }
  uint32_t cl[8], ch[8], dl[8], dh[8];
#pragma unroll
  for (int r = 0; r < 8; ++r) {
    cl[r] = c[r] & 0x00FF00FFu; ch[r] = (c[r] >> 8) & 0x00FF00FFu;
    dl[r] = d[r] & 0x00FF00FFu; dh[r] = (d[r] >> 8) & 0x00FF00FFu;
  }
#pragma unroll
  for (int m = 4; m <= 32; m <<= 1) {
#pragma unroll
    for (int r = 0; r < 8; ++r) {
      cl[r] += __shfl_xor(cl[r], m); ch[r] += __shfl_xor(ch[r], m);
      dl[r] += __shfl_xor(dl[r], m); dh[r] += __shfl_xor(dh[r], m);
    }
  }

  const int w = tid >> 6;
  if ((tid & 63) == 0) {
#pragma unroll
    for (int r = 0; r < 8; ++r) {
      red[w][r] = cl[r];       // obs, u16 slots = bins 4r, 4r+2
      red[w][8 + r] = ch[r];   // obs, bins 4r+1, 4r+3
      red[w][16 + r] = dl[r];  // pred
      red[w][24 + r] = dh[r];
    }
  }
  __syncthreads();

  if (tid < 2 * NBINS) {
    const int arr = tid >> 5;
    const int bin = tid & 31;
    const int slot = arr * 16 + (bin >> 2) + ((bin & 1) ? 8 : 0);
    const int shift = (bin & 2) ? 16 : 0;
    uint32_t s = 0;
#pragma unroll
    for (int wv = 0; wv < 4; ++wv) s += (red[wv][slot] >> shift) & 0xFFFFu;
    if (s) atomicAdd(&ws[(arr ? WS_PRED : 0) + b * NBINS + bin], s);
  }
}

__global__ __launch_bounds__(64) void finalize_kernel(
    const uint32_t* __restrict__ ws, const float* __restrict__ edges,
    float* __restrict__ out) {
  __shared__ float pobs[NBATCH][NBINS + 1];
  __shared__ float ppred[NBATCH][NBINS + 1];
  __shared__ float w_sh[NBINS];
  __shared__ float bw_sh[NBINS];
  __shared__ float w_scale;

  const int t = threadIdx.x;

  const uint32_t* co = ws + t * NBINS;
  const uint32_t* cp = ws + WS_PRED + t * NBINS;
  const uint32_t nmask = ws[WS_NM + t];

  float sum_o = 0.0f, sum_p = 0.0f;
#pragma unroll
  for (int j = 0; j < NBINS; ++j) {
    float vo = (nmask == 0u) ? 1.0f : (float)co[j];
    float vp = (nmask == 0u) ? 1.0f : (float)cp[j];
    pobs[t][j] = vo;  sum_o += vo;
    ppred[t][j] = vp; sum_p += vp;
  }
  const float inv_to = 1.0f / fmaxf(sum_o, 1.0f);
  const float inv_tp = 1.0f / fmaxf(sum_p, 1.0f);
#pragma unroll
  for (int j = 0; j < NBINS; ++j) {
    pobs[t][j] *= inv_to;
    ppred[t][j] = 0.95f * (ppred[t][j] * inv_tp) + 0.05f / (float)NBINS;
  }
  __syncthreads();

  if (t < NBINS) {
    float s = 0.0f;
#pragma unroll
    for (int b = 0; b < NBATCH; ++b) s += pobs[b][t];
    const float avg = s / (float)NBATCH;
    w_sh[t] = 1.0f / (avg + 1e-3f);
    const int j2 = (t < NBINS - 1) ? t : (NBINS - 2);
    const float mA = 0.5f * (edges[j2] + edges[j2 + 1]);
    const float mB = 0.5f * (edges[j2 + 1] + edges[j2 + 2]);
    bw_sh[t] = mB - mA;
  }
  __syncthreads();
  if (t == 0) {
    float sw = 0.0f;
#pragma unroll
    for (int j = 0; j < NBINS; ++j) sw += w_sh[j];
    w_scale = (float)NBINS / sw;
  }
  __syncthreads();

  float ce = 0.0f, w2 = 0.0f, cdf_o = 0.0f, cdf_p = 0.0f;
#pragma unroll
  for (int j = 0; j < NBINS; ++j) {
    const float po = pobs[t][j];
    const float pp = ppred[t][j];
    ce += -po * logf(pp + 1e-8f) * (w_sh[j] * w_scale);
    cdf_o += po;
    cdf_p += pp;
    const float dd = cdf_o - cdf_p;
    w2 += dd * dd * bw_sh[j];
  }

  float ce_r = ce, w2_r = w2;
#pragma unroll
  for (int off = 32; off >= 1; off >>= 1) {
    ce_r += __shfl_down(ce_r, off);
    w2_r += __shfl_down(w2_r, off);
  }
  if (t == 0) {
    const float ce_m = ce_r / (float)NBATCH;
    const float w2_m = w2_r / (float)NBATCH;
    out[0] = (ce_m + 0.1f * w2_m) / (float)NBINS;
    out[1] = ce_m;
    out[2] = w2_m;
  }

#pragma unroll
  for (int j = 0; j < NBINS; ++j) {
    out[3 + t * NBINS + j] = pobs[t][j];
    out[3 + NBATCH * NBINS + t * NBINS + j] = ppred[t][j];
  }
}

extern "C" void kernel_launch(void* const* d_in, const int* in_sizes, int n_in,
                              void* d_out, int out_size, void* d_ws,
                              size_t ws_size, hipStream_t stream) {
  const float* obs = (const float*)d_in[0];
  const float* pred = (const float*)d_in[1];
  const void* mask = d_in[2];
  const float* edges = (const float*)d_in[3];
  float* out = (float*)d_out;
  uint32_t* ws = (uint32_t*)d_ws;

  hipMemsetAsync(d_ws, 0, WS_WORDS * sizeof(uint32_t), stream);
  detect_mask_kernel<<<1, 64, 0, stream>>>((const uint32_t*)mask,
                                           ws + WS_FLAG);
  hist_kernel<<<NBATCH * BPB, TPB, 0, stream>>>(obs, pred, mask, ws);
  finalize_kernel<<<1, 64, 0, stream>>>(ws, edges, out);
}

// Round 7
// 257.685 us; speedup vs baseline: 1.0218x; 1.0218x over previous
//
#include <hip/hip_runtime.h>
#include <stdint.h>

#define NBINS 32
#define NBATCH 64
#define NPB (512 * 512)            // pixels per batch
#define BPB 32                     // blocks per batch
#define TPB 256
#define EPB (NPB / BPB)            // 8192 elems per block
#define KS 8                       // float4 slots per thread (32 pixels)

// ws layout (uint32 words):
//   [0, 2048)      obs counts   [b*32 + j]
//   [2048, 4096)   pred counts  [b*32 + j]
//   [4096, 4160)   n_masked per batch
//   [4160]         mask-format flag: 1 => bytes (bool/u8), 0 => int32
#define WS_PRED 2048
#define WS_NM   4096
#define WS_FLAG 4160
#define WS_WORDS 4161

__global__ void detect_mask_kernel(const uint32_t* __restrict__ mw,
                                   uint32_t* __restrict__ flag) {
  uint32_t v = mw[threadIdx.x];
  if (__any(v > 1u) && threadIdx.x == 0) *flag = 1u;
}

// Exact searchsorted(edges, x, 'right')-1 for edges = linspace(-3,3,33):
// every true edge is an exact multiple of 0.1875f (=3/16), so correct the
// analytic guess against edges rebuilt exactly in-register. Out-of-range /
// masked values land outside [0,31] and fall off the counting tree.
__device__ __forceinline__ int bin_of(float x) {
  float t = __builtin_fmaf(x, 5.333333492279053f, 16.0f);  // (x+3)*32/6
  int i = (int)t;
  float fi = (float)i;
  float elo = __builtin_fmaf(fi, 0.1875f, -3.0f);
  float ehi = elo + 0.1875f;
  i += (x >= ehi) ? 1 : 0;
  i -= (x < elo) ? 1 : 0;
  return i;
}

// Static select-tree increment into 8 byte-packed u32 counters.
__device__ __forceinline__ void count_one(int i, uint32_t h[8]) {
  const uint32_t inc = 1u << ((i & 3) << 3);
  const int hi = i >> 2;
#pragma unroll
  for (int r = 0; r < 8; ++r) h[r] += (hi == r) ? inc : 0u;
}

__global__ __launch_bounds__(TPB) void hist_kernel(
    const float* __restrict__ obs, const float* __restrict__ pred,
    const void* __restrict__ mask, uint32_t* __restrict__ ws) {
  __shared__ uint32_t red[4][32];  // per-wave packed partials

  const int tid = threadIdx.x;
  const uint32_t is_u8 = ws[WS_FLAG];  // uniform
  const int b = blockIdx.x / BPB;
  const int chunk = blockIdx.x % BPB;
  const size_t base_f4 = (((size_t)b * NPB) + ((size_t)chunk * EPB)) >> 2;

  const float4* __restrict__ o4 = (const float4*)obs;
  const float4* __restrict__ p4 = (const float4*)pred;
  const uint32_t* __restrict__ mwp = (const uint32_t*)mask;
  const int4* __restrict__ mip = (const int4*)mask;

  uint32_t c[8] = {0, 0, 0, 0, 0, 0, 0, 0};  // obs byte-packed counters
  uint32_t d[8] = {0, 0, 0, 0, 0, 0, 0, 0};  // pred
  uint32_t nm = 0;

  if (is_u8) {
    // ---- deep-MLP batch: issue ALL 18 loads before any use ----
    uint32_t M[KS];
    float4 O[KS], P[KS];
#pragma unroll
    for (int k = 0; k < KS; ++k)
      M[k] = mwp[base_f4 + (size_t)(k * TPB) + tid];
#pragma unroll
    for (int k = 0; k < KS; ++k)
      O[k] = o4[base_f4 + (size_t)(k * TPB) + tid];
#pragma unroll
    for (int k = 0; k < KS; ++k)
      P[k] = p4[base_f4 + (size_t)(k * TPB) + tid];

    uint32_t nm_pack = 0;
    // obs pass — P loads still in flight, overlapping this VALU work
#pragma unroll
    for (int k = 0; k < KS; ++k) {
      const uint32_t w = M[k];
      nm_pack += w;  // bytes are 0/1; <=8 per byte over 8 adds
      const float a0 = (w & 0x000000ffu) ? O[k].x : 1e2f;
      const float a1 = (w & 0x0000ff00u) ? O[k].y : 1e2f;
      const float a2 = (w & 0x00ff0000u) ? O[k].z : 1e2f;
      const float a3 = (w & 0xff000000u) ? O[k].w : 1e2f;
      count_one(bin_of(a0), c);
      count_one(bin_of(a1), c);
      count_one(bin_of(a2), c);
      count_one(bin_of(a3), c);
    }
    // pred pass
#pragma unroll
    for (int k = 0; k < KS; ++k) {
      const uint32_t w = M[k];
      const float b0 = (w & 0x000000ffu) ? P[k].x : 1e2f;
      const float b1 = (w & 0x0000ff00u) ? P[k].y : 1e2f;
      const float b2 = (w & 0x00ff0000u) ? P[k].z : 1e2f;
      const float b3 = (w & 0xff000000u) ? P[k].w : 1e2f;
      count_one(bin_of(b0), d);
      count_one(bin_of(b1), d);
      count_one(bin_of(b2), d);
      count_one(bin_of(b3), d);
    }
    nm = (nm_pack & 0xffu) + ((nm_pack >> 8) & 0xffu) +
         ((nm_pack >> 16) & 0xffu) + (nm_pack >> 24);
  } else {
    // ---- int32-mask fallback: rolled loop, 1-ahead prefetch ----
    float4 xo = o4[base_f4 + tid], xp = p4[base_f4 + tid];
    int4 mi_c = mip[base_f4 + tid];
#pragma unroll
    for (int it = 0; it < KS; ++it) {
      float4 nxo = xo, nxp = xp;
      int4 nmi = mi_c;
      if (it + 1 < KS) {
        const size_t ni = base_f4 + (size_t)((it + 1) * TPB) + tid;
        nxo = o4[ni]; nxp = p4[ni]; nmi = mip[ni];
      }
      const bool m0 = mi_c.x != 0, m1 = mi_c.y != 0;
      const bool m2 = mi_c.z != 0, m3 = mi_c.w != 0;
      nm += (m0 ? 1u : 0u) + (m1 ? 1u : 0u) + (m2 ? 1u : 0u) + (m3 ? 1u : 0u);
      count_one(bin_of(m0 ? xo.x : 1e2f), c);
      count_one(bin_of(m1 ? xo.y : 1e2f), c);
      count_one(bin_of(m2 ? xo.z : 1e2f), c);
      count_one(bin_of(m3 ? xo.w : 1e2f), c);
      count_one(bin_of(m0 ? xp.x : 1e2f), d);
      count_one(bin_of(m1 ? xp.y : 1e2f), d);
      count_one(bin_of(m2 ? xp.z : 1e2f), d);
      count_one(bin_of(m3 ? xp.w : 1e2f), d);
      xo = nxo; xp = nxp; mi_c = nmi;
    }
  }

  // ---- n_masked: per-wave reduce, one global atomic per wave ----
#pragma unroll
  for (int off = 32; off >= 1; off >>= 1) nm += __shfl_down(nm, off);
  if ((tid & 63) == 0) atomicAdd(&ws[WS_NM + b], nm);

  // ---- butterfly-reduce packed counters across the wave ----
#pragma unroll
  for (int m = 1; m <= 2; m <<= 1) {
#pragma unroll
    for (int r = 0; r < 8; ++r) {
      c[r] += __shfl_xor(c[r], m);
      d[r] += __shfl_xor(d[r], m);
    }
  }
  uint32_t cl[8], ch[8], dl[8], dh[8];
#pragma unroll
  for (int r = 0; r < 8; ++r) {
    cl[r] = c[r] & 0x00FF00FFu; ch[r] = (c[r] >> 8) & 0x00FF00FFu;
    dl[r] = d[r] & 0x00FF00FFu; dh[r] = (d[r] >> 8) & 0x00FF00FFu;
  }
#pragma unroll
  for (int m = 4; m <= 32; m <<= 1) {
#pragma unroll
    for (int r = 0; r < 8; ++r) {
      cl[r] += __shfl_xor(cl[r], m); ch[r] += __shfl_xor(ch[r], m);
      dl[r] += __shfl_xor(dl[r], m); dh[r] += __shfl_xor(dh[r], m);
    }
  }

  const int w = tid >> 6;
  if ((tid & 63) == 0) {
#pragma unroll
    for (int r = 0; r < 8; ++r) {
      red[w][r] = cl[r];       // obs, u16 slots = bins 4r, 4r+2
      red[w][8 + r] = ch[r];   // obs, bins 4r+1, 4r+3
      red[w][16 + r] = dl[r];  // pred
      red[w][24 + r] = dh[r];
    }
  }
  __syncthreads();

  if (tid < 2 * NBINS) {
    const int arr = tid >> 5;
    const int bin = tid & 31;
    const int slot = arr * 16 + (bin >> 2) + ((bin & 1) ? 8 : 0);
    const int shift = (bin & 2) ? 16 : 0;
    uint32_t s = 0;
#pragma unroll
    for (int wv = 0; wv < 4; ++wv) s += (red[wv][slot] >> shift) & 0xFFFFu;
    if (s) atomicAdd(&ws[(arr ? WS_PRED : 0) + b * NBINS + bin], s);
  }
}

__global__ __launch_bounds__(64) void finalize_kernel(
    const uint32_t* __restrict__ ws, const float* __restrict__ edges,
    float* __restrict__ out) {
  __shared__ float pobs[NBATCH][NBINS + 1];
  __shared__ float ppred[NBATCH][NBINS + 1];
  __shared__ float w_sh[NBINS];
  __shared__ float bw_sh[NBINS];
  __shared__ float w_scale;

  const int t = threadIdx.x;

  const uint32_t* co = ws + t * NBINS;
  const uint32_t* cp = ws + WS_PRED + t * NBINS;
  const uint32_t nmask = ws[WS_NM + t];

  float sum_o = 0.0f, sum_p = 0.0f;
#pragma unroll
  for (int j = 0; j < NBINS; ++j) {
    float vo = (nmask == 0u) ? 1.0f : (float)co[j];
    float vp = (nmask == 0u) ? 1.0f : (float)cp[j];
    pobs[t][j] = vo;  sum_o += vo;
    ppred[t][j] = vp; sum_p += vp;
  }
  const float inv_to = 1.0f / fmaxf(sum_o, 1.0f);
  const float inv_tp = 1.0f / fmaxf(sum_p, 1.0f);
#pragma unroll
  for (int j = 0; j < NBINS; ++j) {
    pobs[t][j] *= inv_to;
    ppred[t][j] = 0.95f * (ppred[t][j] * inv_tp) + 0.05f / (float)NBINS;
  }
  __syncthreads();

  if (t < NBINS) {
    float s = 0.0f;
#pragma unroll
    for (int b = 0; b < NBATCH; ++b) s += pobs[b][t];
    const float avg = s / (float)NBATCH;
    w_sh[t] = 1.0f / (avg + 1e-3f);
    const int j2 = (t < NBINS - 1) ? t : (NBINS - 2);
    const float mA = 0.5f * (edges[j2] + edges[j2 + 1]);
    const float mB = 0.5f * (edges[j2 + 1] + edges[j2 + 2]);
    bw_sh[t] = mB - mA;
  }
  __syncthreads();
  if (t == 0) {
    float sw = 0.0f;
#pragma unroll
    for (int j = 0; j < NBINS; ++j) sw += w_sh[j];
    w_scale = (float)NBINS / sw;
  }
  __syncthreads();

  float ce = 0.0f, w2 = 0.0f, cdf_o = 0.0f, cdf_p = 0.0f;
#pragma unroll
  for (int j = 0; j < NBINS; ++j) {
    const float po = pobs[t][j];
    const float pp = ppred[t][j];
    ce += -po * logf(pp + 1e-8f) * (w_sh[j] * w_scale);
    cdf_o += po;
    cdf_p += pp;
    const float dd = cdf_o - cdf_p;
    w2 += dd * dd * bw_sh[j];
  }

  float ce_r = ce, w2_r = w2;
#pragma unroll
  for (int off = 32; off >= 1; off >>= 1) {
    ce_r += __shfl_down(ce_r, off);
    w2_r += __shfl_down(w2_r, off);
  }
  if (t == 0) {
    const float ce_m = ce_r / (float)NBATCH;
    const float w2_m = w2_r / (float)NBATCH;
    out[0] = (ce_m + 0.1f * w2_m) / (float)NBINS;
    out[1] = ce_m;
    out[2] = w2_m;
  }

#pragma unroll
  for (int j = 0; j < NBINS; ++j) {
    out[3 + t * NBINS + j] = pobs[t][j];
    out[3 + NBATCH * NBINS + t * NBINS + j] = ppred[t][j];
  }
}

extern "C" void kernel_launch(void* const* d_in, const int* in_sizes, int n_in,
                              void* d_out, int out_size, void* d_ws,
                              size_t ws_size, hipStream_t stream) {
  const float* obs = (const float*)d_in[0];
  const float* pred = (const float*)d_in[1];
  const void* mask = d_in[2];
  const float* edges = (const float*)d_in[3];
  float* out = (float*)d_out;
  uint32_t* ws = (uint32_t*)d_ws;

  hipMemsetAsync(d_ws, 0, WS_WORDS * sizeof(uint32_t), stream);
  detect_mask_kernel<<<1, 64, 0, stream>>>((const uint32_t*)mask,
                                           ws + WS_FLAG);
  hist_kernel<<<NBATCH * BPB, TPB, 0, stream>>>(obs, pred, mask, ws);
  finalize_kernel<<<1, 64, 0, stream>>>(ws, edges, out);
}